// Round 9
// baseline (952.828 us; speedup 1.0000x reference)
//
#include <hip/hip_runtime.h>
#include <hip/hip_bf16.h>

// Problem constants
#define Lc 256
#define Bc 64
#define Dc 1024
#define Hc 512
#define Rc 8
#define Cc 6
#define WINc 10
#define NWc 21
#define Nc (Bc*Lc)        // 16384
#define DHc (Dc+Hc)       // 1536
#define CH 8192           // RGCN chunk (32 conversations)

typedef __attribute__((ext_vector_type(8))) short short8;
typedef __attribute__((ext_vector_type(4))) float floatx4;

__device__ inline unsigned short f2b(float x) {
    __hip_bfloat16 h = __float2bfloat16(x);
    return *reinterpret_cast<unsigned short*>(&h);
}
__device__ inline float bf2f(unsigned short u) {
    __hip_bfloat16 h;
    *reinterpret_cast<unsigned short*>(&h) = u;
    return __bfloat162float(h);
}

// node id n = b*256+s  ->  feats row s*64+b
__device__ inline long remap_row(int node) { return (long)(((node & 255) << 6) + (node >> 8)); }

typedef __attribute__((address_space(3))) unsigned int lds_u32;
typedef __attribute__((address_space(1))) unsigned int glb_u32;
__device__ inline void glds16(const unsigned short* g, unsigned short* l) {
    __builtin_amdgcn_global_load_lds((const glb_u32*)g, (lds_u32*)l, 16, 0, 0);
}

// ---------------- all weight transposes in ONE launch (fp32 [K][N] -> bf16 [N][K]) ----------------
__global__ __launch_bounds__(256) void transpose_all(
    const float* __restrict__ Wscalar, const float* __restrict__ W_rel,
    const float* __restrict__ W_root, const float* __restrict__ W_nbr,
    const float* __restrict__ W_self, const float* __restrict__ W_match,
    const float* __restrict__ W_lin, unsigned short* __restrict__ WT)
{
    int t = blockIdx.x;
    const float* in; unsigned short* out; int N, ldo, n0, k0;
    if (t < 256) {                       // Wscalar [1024][256] -> [256][1024]
        in = Wscalar; out = WT; N = 256; ldo = 1024;
        n0 = (t & 7) * 32; k0 = (t >> 3) * 32;
    } else if (t < 4352) {               // W_rel 8x[1024][512]
        int u = t - 256; int r = u >> 9; u &= 511;
        in = W_rel + (long)r * 524288; out = WT + 262144 + (long)r * 524288; N = 512; ldo = 1024;
        n0 = (u & 15) * 32; k0 = (u >> 4) * 32;
    } else if (t < 4864) {               // W_root -> WrelT rows 4096..4608
        int u = t - 4352;
        in = W_root; out = WT + 262144 + 4096 * 1024; N = 512; ldo = 1024;
        n0 = (u & 15) * 32; k0 = (u >> 4) * 32;
    } else if (t < 5120) {               // W_nbr -> WgcT k 0..512
        int u = t - 4864;
        in = W_nbr; out = WT + 4980736; N = 512; ldo = 1024;
        n0 = (u & 15) * 32; k0 = (u >> 4) * 32;
    } else if (t < 5376) {               // W_self -> WgcT k 512..1024
        int u = t - 5120;
        in = W_self; out = WT + 4980736 + 512; N = 512; ldo = 1024;
        n0 = (u & 15) * 32; k0 = (u >> 4) * 32;
    } else if (t < 7680) {               // W_match [1536][1536]
        int u = t - 5376;
        in = W_match; out = WT + 5505024; N = 1536; ldo = 1536;
        n0 = (u % 48) * 32; k0 = (u / 48) * 32;
    } else {                             // W_lin [1536][512]
        int u = t - 7680;
        in = W_lin; out = WT + 7864320; N = 512; ldo = 1536;
        n0 = (u & 15) * 32; k0 = (u >> 4) * 32;
    }
    __shared__ float tt[32][33];
    int tx = threadIdx.x & 31, ty = threadIdx.x >> 5;
    #pragma unroll
    for (int i = 0; i < 4; i++) tt[ty + i * 8][tx] = in[(long)(k0 + ty + i * 8) * N + n0 + tx];
    __syncthreads();
    #pragma unroll
    for (int i = 0; i < 4; i++) out[(long)(n0 + ty + i * 8) * ldo + k0 + tx] = f2b(tt[tx][ty + i * 8]);
}

// ---------------- stable partition of each chunk's nodes by speaker ----------------
__global__ __launch_bounds__(256) void partition_kernel(const int* __restrict__ spk,
        int* __restrict__ idx, int* __restrict__ cnts)
{
    int c = blockIdx.x;
    int tid = threadIdx.x;
    int base = c * CH;
    __shared__ int zs[256];
    int zcount = 0;
    for (int i = 0; i < CH / 256; i++) {
        int n = base + tid * (CH / 256) + i;
        if (spk[(n & 255) * 64 + (n >> 8)] == 0) zcount++;
    }
    zs[tid] = zcount; __syncthreads();
    for (int off = 1; off < 256; off <<= 1) {
        int v = (tid >= off) ? zs[tid - off] : 0;
        __syncthreads();
        zs[tid] += v;
        __syncthreads();
    }
    int Z = zs[255];
    int zpos = zs[tid] - zcount;
    int opos = tid * (CH / 256) - zpos;
    for (int i = 0; i < CH / 256; i++) {
        int nl = tid * (CH / 256) + i;
        int n = base + nl;
        if (spk[(n & 255) * 64 + (n >> 8)] == 0) idx[base + (zpos++)] = nl;
        else                                     idx[base + Z + (opos++)] = nl;
    }
    if (tid == 0) cnts[c] = Z;
}

// ---------------- em[:, 0:1024) = bf16(features) in node order ----------------
__global__ __launch_bounds__(256) void build_em_x(const float* __restrict__ feats,
                                                  unsigned short* __restrict__ em)
{
    int n = blockIdx.x;
    int tid = threadIdx.x;
    const float* f = feats + remap_row(n) * Dc;
    float4 v = ((const float4*)f)[tid];
    unsigned short* e = em + (long)n * DHc + tid * 4;
    e[0] = f2b(v.x); e[1] = f2b(v.y); e[2] = f2b(v.z); e[3] = f2b(v.w);
}

// ---------------- MFMA GEMM, async staging, fragment-ordered LDS ----------------
// SPLIT: N=2048 run; cols<1536 -> Cv (normal, bias), cols>=1536 -> Cv2 (transposed emWT, bias2)
template<bool CBF, bool CT, bool BIAS, bool RELU, bool SPLIT>
__global__ __launch_bounds__(256) void gemm_as(
    const unsigned short* __restrict__ A, const unsigned short* __restrict__ B,
    void* __restrict__ Cv, void* __restrict__ Cv2,
    const float* __restrict__ bias, const float* __restrict__ bias2,
    int K, int lda, int ldb, int ldc, long sA, long sB, long sC)
{
    __shared__ __align__(16) unsigned short As[4096];
    __shared__ __align__(16) unsigned short Bs[4096];
    const int tid = threadIdx.x;
    const int z = blockIdx.z;
    const int m0 = blockIdx.y * 128, n0 = blockIdx.x * 128;
    const int lane = tid & 63, wave = tid >> 6;
    const int q = lane >> 4, mr = lane & 15;
    const int wrow = (wave >> 1) * 64, wcol = (wave & 1) * 64;

    const unsigned short* Ag0 = A + z * sA + (long)(m0 + wave * 32 + mr) * lda + q * 8;
    const unsigned short* Ag1 = Ag0 + (long)16 * lda;
    const unsigned short* Bg0 = B + z * sB + (long)(n0 + wave * 32 + mr) * ldb + q * 8;
    const unsigned short* Bg1 = Bg0 + (long)16 * ldb;
    unsigned short* Al0 = As + wave * 1024;
    unsigned short* Bl0 = Bs + wave * 1024;

    floatx4 acc[4][4];
    #pragma unroll
    for (int mt = 0; mt < 4; mt++)
        #pragma unroll
        for (int nt = 0; nt < 4; nt++) acc[mt][nt] = (floatx4){0.f, 0.f, 0.f, 0.f};

    const int ga = (wave >> 1) * 2048;
    const int gb = (wave & 1) * 2048;

    for (int k0 = 0; k0 < K; k0 += 32) {
        glds16(Ag0 + k0, Al0);
        glds16(Ag1 + k0, Al0 + 512);
        glds16(Bg0 + k0, Bl0);
        glds16(Bg1 + k0, Bl0 + 512);
        __syncthreads();
        short8 af[4], bfr[4];
        #pragma unroll
        for (int t = 0; t < 4; t++) {
            af[t]  = *(const short8*)&As[ga + t * 512 + lane * 8];
            bfr[t] = *(const short8*)&Bs[gb + t * 512 + lane * 8];
        }
        #pragma unroll
        for (int mt = 0; mt < 4; mt++)
            #pragma unroll
            for (int nt = 0; nt < 4; nt++)
                acc[mt][nt] = __builtin_amdgcn_mfma_f32_16x16x32_bf16(af[mt], bfr[nt], acc[mt][nt], 0, 0, 0);
        __syncthreads();
    }

    float* Cf = (float*)Cv;
    unsigned short* Cb = (unsigned short*)Cv;
    unsigned short* Cb2 = (unsigned short*)Cv2;
    #pragma unroll
    for (int mt = 0; mt < 4; mt++) {
        #pragma unroll
        for (int nt = 0; nt < 4; nt++) {
            int col = n0 + wcol + nt * 16 + mr;
            float bv = 0.f;
            if (SPLIT) bv = (col < 1536) ? bias[col] : bias2[col - 1536];
            else if (BIAS) bv = bias[col];
            #pragma unroll
            for (int rg = 0; rg < 4; rg++) {
                int row = m0 + wrow + mt * 16 + q * 4 + rg;
                float v = acc[mt][nt][rg] + bv;
                if (RELU) v = fmaxf(v, 0.f);
                if (SPLIT) {
                    if (col < 1536) Cb[(long)row * 1536 + col] = f2b(v);
                    else Cb2[(long)(row >> 8) * 131072 + (long)(col - 1536) * 256 + (row & 255)] = f2b(v);
                } else if (CT) {
                    Cb[(long)(row >> 8) * 131072 + (long)col * 256 + (row & 255)] = f2b(v);
                } else {
                    long ci = z * sC + (long)row * ldc + col;
                    if (CBF) Cb[ci] = f2b(v);
                    else     Cf[ci] = v;
                }
            }
        }
    }
}

// ---------------- row-indexed RGCN GEMM, N=2560 (4 transforms + root) ----------------
template<bool SP1>
__global__ __launch_bounds__(256) void gemm_idx(
    const unsigned short* __restrict__ A, const unsigned short* __restrict__ B,
    unsigned short* __restrict__ C, const int* __restrict__ idx,
    const int* __restrict__ cntp)
{
    const int cnt0 = *cntp;
    const int off  = SP1 ? cnt0 : 0;
    const int M    = SP1 ? (CH - cnt0) : cnt0;
    const int m0 = blockIdx.y * 128;
    if (m0 >= M) return;
    const int n0 = blockIdx.x * 128;
    const int tid = threadIdx.x;
    const int lane = tid & 63, wave = tid >> 6;
    const int q = lane >> 4, mr = lane & 15;
    const int wrow = (wave >> 1) * 64, wcol = (wave & 1) * 64;

    int r0 = m0 + wave * 32 + mr;
    int ar0 = idx[off + min(r0, M - 1)];
    int ar1 = idx[off + min(r0 + 16, M - 1)];
    const unsigned short* Ag0 = A + (long)ar0 * DHc + q * 8;
    const unsigned short* Ag1 = A + (long)ar1 * DHc + q * 8;
    // B row base: cols<2048 -> speaker's 4 transforms; cols>=2048 -> root (rows 4096..)
    long brow = (n0 < 2048) ? (long)((SP1 ? 2048 : 0) + n0) : (long)(4096 + (n0 - 2048));
    const unsigned short* Bg0 = B + (brow + wave * 32 + mr) * 1024 + q * 8;
    const unsigned short* Bg1 = Bg0 + 16 * 1024;

    __shared__ __align__(16) unsigned short As[4096];
    __shared__ __align__(16) unsigned short Bs[4096];
    unsigned short* Al0 = As + wave * 1024;
    unsigned short* Bl0 = Bs + wave * 1024;

    floatx4 acc[4][4];
    #pragma unroll
    for (int mt = 0; mt < 4; mt++)
        #pragma unroll
        for (int nt = 0; nt < 4; nt++) acc[mt][nt] = (floatx4){0.f, 0.f, 0.f, 0.f};

    const int ga = (wave >> 1) * 2048;
    const int gb = (wave & 1) * 2048;

    for (int k0 = 0; k0 < 1024; k0 += 32) {
        glds16(Ag0 + k0, Al0);
        glds16(Ag1 + k0, Al0 + 512);
        glds16(Bg0 + k0, Bl0);
        glds16(Bg1 + k0, Bl0 + 512);
        __syncthreads();
        short8 af[4], bfr[4];
        #pragma unroll
        for (int t = 0; t < 4; t++) {
            af[t]  = *(const short8*)&As[ga + t * 512 + lane * 8];
            bfr[t] = *(const short8*)&Bs[gb + t * 512 + lane * 8];
        }
        #pragma unroll
        for (int mt = 0; mt < 4; mt++)
            #pragma unroll
            for (int nt = 0; nt < 4; nt++)
                acc[mt][nt] = __builtin_amdgcn_mfma_f32_16x16x32_bf16(af[mt], bfr[nt], acc[mt][nt], 0, 0, 0);
        __syncthreads();
    }

    #pragma unroll
    for (int mt = 0; mt < 4; mt++) {
        #pragma unroll
        for (int nt = 0; nt < 4; nt++) {
            int col = n0 + wcol + nt * 16 + mr;
            #pragma unroll
            for (int rg = 0; rg < 4; rg++) {
                int row = m0 + wrow + mt * 16 + q * 4 + rg;
                int crow = idx[off + min(row, M - 1)];
                C[(long)crow * 2560 + col] = f2b(acc[mt][nt][rg]);
            }
        }
    }
}

// ---------------- edge_norm: windowed softmax over k ----------------
__global__ __launch_bounds__(256) void edge_norm_kernel(const float* __restrict__ scale,
                                                        float* __restrict__ enorm)
{
    int g = blockIdx.x * 256 + threadIdx.x;   // b*L + j
    int b = g >> 8, j = g & 255;
    int klo = max(0, j - WINc), khi = min(Lc - 1, j + WINc);
    float vals[NWc];
    float m = -1e30f;
    for (int k = klo; k <= khi; k++) {
        float v = scale[(long)((b << 8) + k) * Lc + j];
        vals[k - klo] = v;
        m = fmaxf(m, v);
    }
    float s = 0.f;
    for (int k = klo; k <= khi; k++) {
        float e = expf(vals[k - klo] - m);
        vals[k - klo] = e;
        s += e;
    }
    float inv = 1.f / s;
    for (int k = klo; k <= khi; k++)
        enorm[(long)g * NWc + (k - j + WINc)] = vals[k - klo] * inv;
}

// ---------------- RGCN aggregation (hall4 bf16 [CH][2560]) ----------------
__global__ __launch_bounds__(256) void rgcn_gather4(const unsigned short* __restrict__ hall4,
        const float* __restrict__ enorm, const int* __restrict__ spk,
        const float* __restrict__ b_rgcn, float* __restrict__ h1, int chunk_base)
{
    int nloc = blockIdx.x;
    int n = chunk_base + nloc;
    int b = n >> 8, k = n & 255;
    int tid = threadIdx.x;
    int spkk = spk[k * 64 + b];
    int jlo = max(0, k - WINc), jhi = min(Lc - 1, k + WINc);
    unsigned int ru = *(const unsigned int*)(hall4 + (long)nloc * 2560 + 2048 + 2 * tid);
    float a0 = bf2f((unsigned short)(ru & 0xffff)) + b_rgcn[2 * tid];
    float a1 = bf2f((unsigned short)(ru >> 16)) + b_rgcn[2 * tid + 1];
    int cb = spkk * 2;
    for (int j = jlo; j <= jhi; j++) {
        int c = cb + ((j < k) ? 0 : 1);
        float w = enorm[((long)((b << 8) + j)) * NWc + (k - j + WINc)];
        unsigned int u = *(const unsigned int*)(hall4 + ((long)(nloc - k + j)) * 2560 + c * 512 + 2 * tid);
        a0 += w * bf2f((unsigned short)(u & 0xffff));
        a1 += w * bf2f((unsigned short)(u >> 16));
    }
    *(float2*)&h1[(long)n * Hc + 2 * tid] = make_float2(a0, a1);
}

// ---------------- anh1 = bf16[ concat(window-sum(h1), h1) ] ----------------
__global__ __launch_bounds__(256) void build_anh1(const float* __restrict__ h1,
                                                  unsigned short* __restrict__ anh1)
{
    int n = blockIdx.x;
    int b = n >> 8, k = n & 255;
    int tid = threadIdx.x;
    int jlo = max(0, k - WINc), jhi = min(Lc - 1, k + WINc);
    float a0 = 0.f, a1 = 0.f;
    for (int j = jlo; j <= jhi; j++) {
        const float* src = h1 + ((long)((b << 8) + j)) * Hc;
        a0 += src[tid];
        a1 += src[tid + 256];
    }
    unsigned short* dst = anh1 + (long)n * 1024;
    const float* self = h1 + (long)n * Hc;
    dst[tid]       = f2b(a0);
    dst[tid + 256] = f2b(a1);
    dst[tid + 512] = f2b(self[tid]);
    dst[tid + 768] = f2b(self[tid + 256]);
}

// ---------------- fused: a = softmax(tanh(S)) [shift=1: tanh<=1], hidden = relu(a @ emW) ----------------
__global__ __launch_bounds__(256) void attn_out(const float* __restrict__ S,
        const unsigned short* __restrict__ emWT, unsigned short* __restrict__ hidden)
{
    __shared__ __align__(16) unsigned short As[4096];
    __shared__ __align__(16) unsigned short Bs[4096];
    __shared__ float rinv[128];
    const int tid = threadIdx.x;
    const int z = blockIdx.z;
    const int m0 = blockIdx.y * 128, n0 = blockIdx.x * 128;
    const int lane = tid & 63, wave = tid >> 6;
    const int q = lane >> 4, mr = lane & 15;
    const int wrow = (wave >> 1) * 64, wcol = (wave & 1) * 64;
    const float* Sb = S + (long)z * 65536;

    // per-row sum of exp(tanh(s) - 1) over 256 cols (2 threads per row)
    {
        int r2 = tid >> 1, half = tid & 1;
        const float* p = Sb + (long)(m0 + r2) * 256 + half * 128;
        float l = 0.f;
        for (int i = 0; i < 128; i += 4) {
            float4 v = *(const float4*)(p + i);
            l += expf(tanhf(v.x) - 1.f) + expf(tanhf(v.y) - 1.f)
               + expf(tanhf(v.z) - 1.f) + expf(tanhf(v.w) - 1.f);
        }
        l += __shfl_xor(l, 1, 64);
        if (half == 0) rinv[r2] = 1.f / l;
    }
    __syncthreads();

    const int r = tid & 127, hh = tid >> 7;
    const float* Srow = Sb + (long)(m0 + r) * 256;
    const float inv_r = rinv[r];
    unsigned short* Adst = As + (r >> 5) * 1024 + ((r >> 4) & 1) * 512 + (r & 15) * 8;
    const unsigned short* Bg0 = emWT + (long)z * 131072 + (long)(n0 + wave * 32 + mr) * 256 + q * 8;
    const unsigned short* Bg1 = Bg0 + 16 * 256;
    unsigned short* Bl0 = Bs + wave * 1024;

    floatx4 acc[4][4];
    #pragma unroll
    for (int mt = 0; mt < 4; mt++)
        #pragma unroll
        for (int nt = 0; nt < 4; nt++) acc[mt][nt] = (floatx4){0.f, 0.f, 0.f, 0.f};

    const int ga = (wave >> 1) * 2048;
    const int gb = (wave & 1) * 2048;

    for (int k0 = 0; k0 < 256; k0 += 32) {
        glds16(Bg0 + k0, Bl0);
        glds16(Bg1 + k0, Bl0 + 512);
        const float* sp = Srow + k0 + hh * 16;
        float4 v0 = *(const float4*)(sp);
        float4 v1 = *(const float4*)(sp + 4);
        float4 v2 = *(const float4*)(sp + 8);
        float4 v3 = *(const float4*)(sp + 12);
        __align__(16) unsigned short tmp[16];
        tmp[0]  = f2b(expf(tanhf(v0.x) - 1.f) * inv_r);
        tmp[1]  = f2b(expf(tanhf(v0.y) - 1.f) * inv_r);
        tmp[2]  = f2b(expf(tanhf(v0.z) - 1.f) * inv_r);
        tmp[3]  = f2b(expf(tanhf(v0.w) - 1.f) * inv_r);
        tmp[4]  = f2b(expf(tanhf(v1.x) - 1.f) * inv_r);
        tmp[5]  = f2b(expf(tanhf(v1.y) - 1.f) * inv_r);
        tmp[6]  = f2b(expf(tanhf(v1.z) - 1.f) * inv_r);
        tmp[7]  = f2b(expf(tanhf(v1.w) - 1.f) * inv_r);
        tmp[8]  = f2b(expf(tanhf(v2.x) - 1.f) * inv_r);
        tmp[9]  = f2b(expf(tanhf(v2.y) - 1.f) * inv_r);
        tmp[10] = f2b(expf(tanhf(v2.z) - 1.f) * inv_r);
        tmp[11] = f2b(expf(tanhf(v2.w) - 1.f) * inv_r);
        tmp[12] = f2b(expf(tanhf(v3.x) - 1.f) * inv_r);
        tmp[13] = f2b(expf(tanhf(v3.y) - 1.f) * inv_r);
        tmp[14] = f2b(expf(tanhf(v3.z) - 1.f) * inv_r);
        tmp[15] = f2b(expf(tanhf(v3.w) - 1.f) * inv_r);
        *(short8*)(Adst + (hh * 2) * 128)     = *(short8*)&tmp[0];
        *(short8*)(Adst + (hh * 2 + 1) * 128) = *(short8*)&tmp[8];
        __syncthreads();
        short8 af[4], bfr[4];
        #pragma unroll
        for (int t = 0; t < 4; t++) {
            af[t]  = *(const short8*)&As[ga + t * 512 + lane * 8];
            bfr[t] = *(const short8*)&Bs[gb + t * 512 + lane * 8];
        }
        #pragma unroll
        for (int mt = 0; mt < 4; mt++)
            #pragma unroll
            for (int nt = 0; nt < 4; nt++)
                acc[mt][nt] = __builtin_amdgcn_mfma_f32_16x16x32_bf16(af[mt], bfr[nt], acc[mt][nt], 0, 0, 0);
        __syncthreads();
    }

    #pragma unroll
    for (int mt = 0; mt < 4; mt++) {
        #pragma unroll
        for (int nt = 0; nt < 4; nt++) {
            int col = n0 + wcol + nt * 16 + mr;
            #pragma unroll
            for (int rg = 0; rg < 4; rg++) {
                int row = m0 + wrow + mt * 16 + q * 4 + rg;
                float v = fmaxf(acc[mt][nt][rg], 0.f);
                hidden[(long)(z * 256 + row) * 512 + col] = f2b(v);
            }
        }
    }
}

// ---------------- final classifier + log_softmax (fp32 out) ----------------
__global__ __launch_bounds__(256) void out_kernel(const unsigned short* __restrict__ hidden,
        const float* __restrict__ Wfc, const float* __restrict__ bfc, float* __restrict__ out)
{
    int tid = threadIdx.x;
    int lane = tid & 63;
    int row = blockIdx.x * 4 + (tid >> 6);
    float acc[Cc] = {};
    const unsigned short* h = hidden + (long)row * Hc;
    for (int k = lane; k < Hc; k += 64) {
        float hv = bf2f(h[k]);
        #pragma unroll
        for (int c = 0; c < Cc; c++) acc[c] += hv * Wfc[k * Cc + c];
    }
    #pragma unroll
    for (int c = 0; c < Cc; c++)
        for (int off = 32; off > 0; off >>= 1) acc[c] += __shfl_down(acc[c], off, 64);
    if (lane == 0) {
        float m = -1e30f;
        #pragma unroll
        for (int c = 0; c < Cc; c++) { acc[c] += bfc[c]; m = fmaxf(m, acc[c]); }
        float s = 0.f;
        #pragma unroll
        for (int c = 0; c < Cc; c++) s += expf(acc[c] - m);
        float lse = logf(s);
        #pragma unroll
        for (int c = 0; c < Cc; c++) out[(long)row * Cc + c] = acc[c] - m - lse;
    }
}

extern "C" void kernel_launch(void* const* d_in, const int* in_sizes, int n_in,
                              void* d_out, int out_size, void* d_ws, size_t ws_size,
                              hipStream_t stream)
{
    const float* feats   = (const float*)d_in[0];
    const float* Wscalar = (const float*)d_in[1];
    const float* W_rel   = (const float*)d_in[2];
    const float* W_root  = (const float*)d_in[3];
    const float* b_rgcn  = (const float*)d_in[4];
    const float* W_nbr   = (const float*)d_in[5];
    const float* W_self  = (const float*)d_in[6];
    const float* b_gc    = (const float*)d_in[7];
    const float* W_match = (const float*)d_in[8];
    const float* b_match = (const float*)d_in[9];
    const float* W_lin   = (const float*)d_in[10];
    const float* b_lin   = (const float*)d_in[11];
    const float* W_fc    = (const float*)d_in[12];
    const float* b_fc    = (const float*)d_in[13];
    const int*   spk     = (const int*)d_in[14];

    char* wsb = (char*)d_ws;
    // em [0, 48M) persistent bf16 concat(x, h2)
    unsigned short* em    = (unsigned short*)wsb;
    // RB [48M, 96M): scale -> hall4(+idx in tail) -> anh1 -> xt -> hidden
    char* RB = wsb + 50331648;
    float*          scale = (float*)RB;                         // 16M
    unsigned short* hall4 = (unsigned short*)RB;                // 41.9M
    int*            idx   = (int*)(RB + 44040192);              // 64K (tail of RB, clear of hall4)
    int*            cnts  = (int*)(RB + 44105728);              // 8B
    unsigned short* anh1  = (unsigned short*)RB;                // 32M
    unsigned short* xt    = (unsigned short*)RB;                // 48M
    unsigned short* hidden= (unsigned short*)RB;                // 16M (xt dead)
    // HB [96M, 128M): h1 -> S | emWT
    char* HB = wsb + 100663296;
    float*          h1    = (float*)HB;                         // 32M
    float*          S     = (float*)HB;                         // 16M (h1 dead)
    unsigned short* emWT  = (unsigned short*)(HB + 16777216);   // 16M (h1 dead)
    // WT [128M, 145.3M) persistent; enorm after
    unsigned short* WT    = (unsigned short*)(wsb + 134217728);
    unsigned short* WscalarT = WT;
    unsigned short* WrelT    = WT + 262144;      // 4608x1024: rels 0..7 then root
    unsigned short* WgcT     = WT + 4980736;     // 512x1024
    unsigned short* WmatchT  = WT + 5505024;     // 1536x1536 (contiguous with WlinT -> 2048 rows)
    unsigned short* WlinT    = WT + 7864320;     // 512x1536
    float*          enorm = (float*)(wsb + 151519232);          // 1.31M -> end 152.9MB

    // ---- 0. transposes, partition, em features
    transpose_all<<<dim3(8448), 256, 0, stream>>>(Wscalar, W_rel, W_root, W_nbr, W_self,
                                                  W_match, W_lin, WT);
    partition_kernel<<<dim3(2), 256, 0, stream>>>(spk, idx, cnts);
    build_em_x<<<dim3(Nc), 256, 0, stream>>>(feats, em);

    // ---- 1. scale = x @ Wscalar
    gemm_as<false, false, false, false, false><<<dim3(2, 128, 1), 256, 0, stream>>>(
        em, WscalarT, scale, nullptr, nullptr, nullptr, 1024, DHc, 1024, 256, 0, 0, 0);

    // ---- 2. windowed softmax
    edge_norm_kernel<<<dim3(64), 256, 0, stream>>>(scale, enorm);

    // ---- 3. RGCN per chunk: speaker-split GEMMs (4 transforms + root cols), gather
    for (int c = 0; c < 2; c++) {
        const unsigned short* emc = em + (long)c * CH * DHc;
        gemm_idx<false><<<dim3(20, 64, 1), 256, 0, stream>>>(
            emc, WrelT, hall4, idx + c * CH, cnts + c);
        gemm_idx<true><<<dim3(20, 64, 1), 256, 0, stream>>>(
            emc, WrelT, hall4, idx + c * CH, cnts + c);
        rgcn_gather4<<<dim3(CH), 256, 0, stream>>>(hall4, enorm, spk, b_rgcn, h1, c * CH);
    }

    // ---- 4. anh1 = concat(window-sum(h1), h1); h2 -> em[:, 1024:1536)
    build_anh1<<<dim3(Nc), 256, 0, stream>>>(h1, anh1);
    gemm_as<true, false, true, false, false><<<dim3(4, 128, 1), 256, 0, stream>>>(
        anh1, WgcT, em + 1024, nullptr, b_gc, nullptr, 1024, 1024, 1024, DHc, 0, 0, 0);

    // ---- 5. merged: [xt | emWT] = em @ [W_match | W_lin] + [b_match | b_lin]
    gemm_as<true, false, true, false, true><<<dim3(16, 128, 1), 256, 0, stream>>>(
        em, WmatchT, xt, emWT, b_match, b_lin, DHc, DHc, DHc, DHc, 0, 0, 0);

    // ---- 6. S_b = xt_b @ em_b^T (z = 64 convs)
    gemm_as<false, false, false, false, false><<<dim3(2, 2, 64), 256, 0, stream>>>(
        xt, em, S, nullptr, nullptr, nullptr, DHc, DHc, DHc, 256, 393216, 393216, 65536);

    // ---- 7. fused softmax(tanh(S)) @ emW -> hidden (relu)
    attn_out<<<dim3(4, 2, 64), 256, 0, stream>>>(S, emWT, hidden);

    // ---- 8. logits + log_softmax
    out_kernel<<<dim3(Nc / 4), 256, 0, stream>>>(hidden, W_fc, b_fc, (float*)d_out);
}